// Round 3
// baseline (112.771 us; speedup 1.0000x reference)
//
#include <hip/hip_runtime.h>

// SoftNCutsLoss on MI355X — R3.
// batch: (4,1,32,32,32) f32, preds: (4,8,32,32,32) f32 -> out: (4,) f32
//
// R3 change vs R2 (theory: 9.32M conflict cycles = owned-voxel lane pattern,
// strides SY=14/SX=140 give per-bank max 4 -> +2 cyc on every ds_read;
// 514K wave-offsets * 9 reads * 2 = 9.25M, matches counter exactly):
//  - halo layout strides SY=16, SX=168 (SX % 32 == 8): lane-group bank bases
//    {0,16,0,16,8,24,8,24} -> every bank exactly 2 lanes = wave64 minimum = free.
//  - all 9 planes in one LDS array, plane stride PS=1672: inner-loop reads are
//    one shared swizzled index + immediate plane offsets.
//  - LDS 60.2 KB -> 2 blocks/CU (accepted: conflict removal > wave count).

#define EPS_F 2.220446049250313e-16f

constexpr int TD = 4, TH = 4, TW = 8;      // tile dims (d,h,w)
constexpr int HD = 10, HH = 10, HW = 14;   // halo dims (+3 each side)
constexpr int HVOL = HD * HH * HW;         // 1400 (compact, staging only)
constexpr int SX = 168;                    // d-stride in LDS (== 8 mod 32)
constexpr int SY = 16;                     // h-stride in LDS
constexpr int PS = 1672;                   // plane stride (>= 9*168+9*16+14)
constexpr int NT = 256;                    // threads per block (4 waves)
constexpr int NBLK = 1024;                 // 4 batches * 256 tiles

// exp(-s^2/16) for s^2 in {0,1,4,9}
#define EX0 1.0f
#define EX1 0.93941306281347578611f
#define EX4 0.77880078307140486825f
#define EX9 0.56978282473092302544f

template <int HALF>
__device__ __forceinline__ void accum_offsets(const float* __restrict__ sData,
                                              int vown, float b_own,
                                              float acc[9]) {
    constexpr float EXT[10] = {EX0, EX1, 0.f, 0.f, EX4, 0.f, 0.f, 0.f, 0.f, EX9};
    constexpr int NDY = HALF ? 3 : 4;
    constexpr int DYI[4] = {HALF ? 1 : 0, HALF ? 3 : 2, HALF ? 5 : 4, HALF ? 7 : 6};

    for (int dxi = 0; dxi < 7; ++dxi) {
        const int dx  = dxi - 3;
        const int dxx = dx * dx;                         // runtime, wave-uniform
        const float wdx = __expf((float)dxx * -0.0625f);
        const int base = vown + (dxi - 3) * SX;          // depth shift
#pragma unroll
        for (int yy = 0; yy < NDY; ++yy) {
            const int dyi = DYI[yy];                     // constant after unroll
            const int dy  = dyi - 3;
            const int c2y = dy * dy;
#pragma unroll
            for (int dzi = 0; dzi < 7; ++dzi) {
                const int dz = dzi - 3;
                const int c2 = c2y + dz * dz;            // compile-time
                if (c2 >= 16) continue;                  // folded at compile time
                if (dxx + c2 >= 16) continue;            // uniform scalar branch
                const float wyz = EXT[c2y] * EXT[dz * dz];
                const int nv = base + dy * SY + dz;      // shared by all 9 reads
                const float sb = sData[nv];
                const float d = b_own - sb;
                const float aff = __expf(d * d * -0.01f) * (wdx * wyz);
                acc[8] += aff;
#pragma unroll
                for (int k = 0; k < 8; ++k)
                    acc[k] += aff * sData[(k + 1) * PS + nv];
            }
        }
    }
}

__global__ __launch_bounds__(NT, 2)
void softncuts_main(const float* __restrict__ batch,
                    const float* __restrict__ preds,
                    float* __restrict__ partials) {
    __shared__ float sData[9 * PS];     // plane 0 = batch, planes 1..8 = classes
    __shared__ float sRed[4][16];

    const int bid  = blockIdx.x;
    const int bb   = bid >> 8;          // batch index 0..3
    const int tile = bid & 255;
    const int tw = tile & 3;            // 0..3  -> w0 = tw*8
    const int th = (tile >> 2) & 7;     // 0..7  -> h0 = th*4
    const int td = tile >> 5;           // 0..7  -> d0 = td*4
    const int d0 = td * TD, h0 = th * TH, w0 = tw * TW;

    const int tid  = threadIdx.x;
    const int half = tid >> 7;          // wave-uniform (waves 0,1 vs 2,3)
    const int vtid = tid & 127;
    const int lw = vtid & 7;            // 0..7
    const int lh = (vtid >> 3) & 3;     // 0..3
    const int ld = vtid >> 5;           // 0..3

    // ---- stage halo tile (OOB -> EPS, matching ConstantPad3d(radius-1, eps)) ----
    const float* bbase = batch + (size_t)bb * 32768;
    const float* pbase = preds + (size_t)bb * 8 * 32768;
    for (int v = tid; v < HVOL; v += NT) {
        int hw_ = v % HW;
        int t   = v / HW;
        int hh_ = t % HH;
        int hd_ = t / HH;
        int f   = hd_ * SX + hh_ * SY + hw_;   // swizzled LDS index
        int gd = d0 + hd_ - 3, gh = h0 + hh_ - 3, gw = w0 + hw_ - 3;
        bool in = ((unsigned)gd < 32u) & ((unsigned)gh < 32u) & ((unsigned)gw < 32u);
        int sidx = (gd * 32 + gh) * 32 + gw;
        sData[f] = in ? bbase[sidx] : EPS_F;
#pragma unroll
        for (int k = 0; k < 8; ++k)
            sData[(k + 1) * PS + f] = in ? pbase[sidx + k * 32768] : EPS_F;
    }
    __syncthreads();

    // ---- main accumulation over this half's window offsets ----
    const int vown = (ld + 3) * SX + (lh + 3) * SY + (lw + 3);
    const float b_own = sData[vown];

    float acc[9];
#pragma unroll
    for (int i = 0; i < 9; ++i) acc[i] = 0.f;

    if (half == 0) accum_offsets<0>(sData, vown, b_own, acc);
    else           accum_offsets<1>(sData, vown, b_own, acc);

    // ---- per-block partial assocA / assocV ----
    float q[8];
#pragma unroll
    for (int k = 0; k < 8; ++k) q[k] = sData[(k + 1) * PS + vown];

    float vals[16];
#pragma unroll
    for (int k = 0; k < 8; ++k) {
        vals[k]     = acc[k] * q[k];
        vals[8 + k] = acc[8] * q[k];
    }

#pragma unroll
    for (int i = 0; i < 16; ++i) {
        float s = vals[i];
        for (int off = 32; off; off >>= 1) s += __shfl_down(s, off);
        vals[i] = s;
    }
    const int wave = tid >> 6;
    const int lane = tid & 63;
    if (lane == 0) {
#pragma unroll
        for (int i = 0; i < 16; ++i) sRed[wave][i] = vals[i];
    }
    __syncthreads();
    if (tid < 16) {
        partials[tid * NBLK + bid] =
            sRed[0][tid] + sRed[1][tid] + sRed[2][tid] + sRed[3][tid];
    }
}

__global__ __launch_bounds__(1024)
void softncuts_finalize(const float* __restrict__ partials,
                        float* __restrict__ out) {
    __shared__ float red[64];
    const int tid = threadIdx.x;          // 0..1023
    const int group = tid >> 4;           // 0..63 = bb*16 + slot
    const int j0 = tid & 15;
    const int slot = group & 15;
    const int bb = group >> 4;

    const float* p = partials + slot * NBLK + bb * 256;
    float s = 0.f;
#pragma unroll
    for (int k = 0; k < 16; ++k) s += p[j0 + 16 * k];
    for (int off = 8; off; off >>= 1) s += __shfl_down(s, off, 16);
    if (j0 == 0) red[group] = s;
    __syncthreads();

    if (tid < 4) {
        float accv = 0.f;
#pragma unroll
        for (int k = 0; k < 8; ++k)
            accv += red[tid * 16 + k] / red[tid * 16 + 8 + k];
        out[tid] = 8.0f - accv;
    }
}

extern "C" void kernel_launch(void* const* d_in, const int* in_sizes, int n_in,
                              void* d_out, int out_size, void* d_ws, size_t ws_size,
                              hipStream_t stream) {
    const float* batch = (const float*)d_in[0];
    const float* preds = (const float*)d_in[1];
    float* out      = (float*)d_out;
    float* partials = (float*)d_ws;   // 16*NBLK floats = 64 KB

    softncuts_main<<<dim3(NBLK), dim3(NT), 0, stream>>>(batch, preds, partials);
    softncuts_finalize<<<dim3(1), dim3(1024), 0, stream>>>(partials, out);
}

// Round 4
// 98.662 us; speedup vs baseline: 1.1430x; 1.1430x over previous
//
#include <hip/hip_runtime.h>
#include <hip/hip_fp16.h>

// SoftNCutsLoss on MI355X — R4.
// batch: (4,1,32,32,32) f32, preds: (4,8,32,32,32) f32 -> out: (4,) f32
//
// R4 theory: R1-R3 are latency-bound at 2 waves/SIMD (60.9 KB LDS -> 2 blocks/CU,
// VALUBusy 33%, both pipes <35% of peak). SQ_LDS_BANK_CONFLICT ~9.3M is invariant
// across three layouts == ~2x inner-loop wave-reads -> it's counting inherent
// wave64 2-phase access, not fixable conflicts. Fix occupancy instead:
//  - preds LDS planes in fp16 (ds_read_u16 + v_fma_mix): LDS 60.9 -> 32.5 KB
//    -> 4-5 blocks/CU, all 1024 blocks co-resident.
//  - own-voxel q[8] and b_own read from global f32 (only neighbor factor is fp16;
//    error ~5e-4 rel << 9e-2 threshold).

#define EPS_F 2.220446049250313e-16f

constexpr int TD = 4, TH = 4, TW = 8;      // tile dims (d,h,w)
constexpr int HD = 10, HH = 10, HW = 14;   // halo dims (+3 each side)
constexpr int HVOL = HD * HH * HW;         // 1400 (compact, staging loop bound)
constexpr int SXB = 168;                   // sB d-stride (f32, == 8 mod 32)
constexpr int SYB = 16;                    // sB h-stride
constexpr int NB  = 1672;                  // sB plane size
constexpr int SXH = 160;                   // sPh d-stride (halves)
constexpr int SYH = 16;                    // sPh h-stride
constexpr int PSH = 1600;                  // sPh plane stride (halves)
constexpr int NT = 256;                    // threads per block (4 waves)
constexpr int NBLK = 1024;                 // 4 batches * 256 tiles

// exp(-s^2/16) for s^2 in {0,1,4,9}
#define EX0 1.0f
#define EX1 0.93941306281347578611f
#define EX4 0.77880078307140486825f
#define EX9 0.56978282473092302544f

template <int HALF>
__device__ __forceinline__ void accum_offsets(const float* __restrict__ sB,
                                              const __half* __restrict__ sPh,
                                              int vownB, int vownH, float b_own,
                                              float acc[9]) {
    constexpr float EXT[10] = {EX0, EX1, 0.f, 0.f, EX4, 0.f, 0.f, 0.f, 0.f, EX9};
    constexpr int NDY = HALF ? 3 : 4;
    constexpr int DYI[4] = {HALF ? 1 : 0, HALF ? 3 : 2, HALF ? 5 : 4, HALF ? 7 : 6};

    for (int dxi = 0; dxi < 7; ++dxi) {
        const int dx  = dxi - 3;
        const int dxx = dx * dx;                         // runtime, wave-uniform
        const float wdx = __expf((float)dxx * -0.0625f);
        const int baseB = vownB + (dxi - 3) * SXB;
        const int baseH = vownH + (dxi - 3) * SXH;
#pragma unroll
        for (int yy = 0; yy < NDY; ++yy) {
            const int dyi = DYI[yy];                     // constant after unroll
            const int dy  = dyi - 3;
            const int c2y = dy * dy;
#pragma unroll
            for (int dzi = 0; dzi < 7; ++dzi) {
                const int dz = dzi - 3;
                const int c2 = c2y + dz * dz;            // compile-time
                if (c2 >= 16) continue;                  // folded at compile time
                if (dxx + c2 >= 16) continue;            // uniform scalar branch
                const float wyz = EXT[c2y] * EXT[dz * dz];
                const int nvB = baseB + dy * SYB + dz;
                const int nvH = baseH + dy * SYH + dz;
                const float sb = sB[nvB];
                const float d = b_own - sb;
                const float aff = __expf(d * d * -0.01f) * (wdx * wyz);
                acc[8] += aff;
#pragma unroll
                for (int k = 0; k < 8; ++k)
                    acc[k] += aff * __half2float(sPh[k * PSH + nvH]);
            }
        }
    }
}

__global__ __launch_bounds__(NT, 4)
void softncuts_main(const float* __restrict__ batch,
                    const float* __restrict__ preds,
                    float* __restrict__ partials) {
    __shared__ float  sB[NB];           // batch halo, f32, swizzled strides
    __shared__ __half sPh[8 * PSH];     // preds halo planes, fp16
    __shared__ float  sRed[4][16];

    const int bid  = blockIdx.x;
    const int bb   = bid >> 8;          // batch index 0..3
    const int tile = bid & 255;
    const int tw = tile & 3;            // 0..3  -> w0 = tw*8
    const int th = (tile >> 2) & 7;     // 0..7  -> h0 = th*4
    const int td = tile >> 5;           // 0..7  -> d0 = td*4
    const int d0 = td * TD, h0 = th * TH, w0 = tw * TW;

    const int tid  = threadIdx.x;
    const int half = tid >> 7;          // wave-uniform (waves 0,1 vs 2,3)
    const int vtid = tid & 127;
    const int lw = vtid & 7;            // 0..7
    const int lh = (vtid >> 3) & 3;     // 0..3
    const int ld = vtid >> 5;           // 0..3

    // ---- stage halo tile (OOB -> EPS, matching ConstantPad3d(radius-1, eps)) ----
    const float* bbase = batch + (size_t)bb * 32768;
    const float* pbase = preds + (size_t)bb * 8 * 32768;
    for (int v = tid; v < HVOL; v += NT) {
        int hw_ = v % HW;
        int t   = v / HW;
        int hh_ = t % HH;
        int hd_ = t / HH;
        int fB = hd_ * SXB + hh_ * SYB + hw_;
        int fH = hd_ * SXH + hh_ * SYH + hw_;
        int gd = d0 + hd_ - 3, gh = h0 + hh_ - 3, gw = w0 + hw_ - 3;
        bool in = ((unsigned)gd < 32u) & ((unsigned)gh < 32u) & ((unsigned)gw < 32u);
        int sidx = (gd * 32 + gh) * 32 + gw;
        sB[fB] = in ? bbase[sidx] : EPS_F;
#pragma unroll
        for (int k = 0; k < 8; ++k)
            sPh[k * PSH + fH] = __float2half(in ? pbase[sidx + k * 32768] : 0.f);
    }
    __syncthreads();

    // ---- own voxel values from GLOBAL f32 (full precision for b_own and q) ----
    const int sidx_own = ((d0 + ld) * 32 + (h0 + lh)) * 32 + (w0 + lw);
    const float b_own = bbase[sidx_own];
    float q[8];
#pragma unroll
    for (int k = 0; k < 8; ++k) q[k] = pbase[sidx_own + k * 32768];

    const int vownB = (ld + 3) * SXB + (lh + 3) * SYB + (lw + 3);
    const int vownH = (ld + 3) * SXH + (lh + 3) * SYH + (lw + 3);

    float acc[9];
#pragma unroll
    for (int i = 0; i < 9; ++i) acc[i] = 0.f;

    if (half == 0) accum_offsets<0>(sB, sPh, vownB, vownH, b_own, acc);
    else           accum_offsets<1>(sB, sPh, vownB, vownH, b_own, acc);

    // ---- per-block partial assocA / assocV ----
    float vals[16];
#pragma unroll
    for (int k = 0; k < 8; ++k) {
        vals[k]     = acc[k] * q[k];
        vals[8 + k] = acc[8] * q[k];
    }

#pragma unroll
    for (int i = 0; i < 16; ++i) {
        float s = vals[i];
        for (int off = 32; off; off >>= 1) s += __shfl_down(s, off);
        vals[i] = s;
    }
    const int wave = tid >> 6;
    const int lane = tid & 63;
    if (lane == 0) {
#pragma unroll
        for (int i = 0; i < 16; ++i) sRed[wave][i] = vals[i];
    }
    __syncthreads();
    if (tid < 16) {
        partials[tid * NBLK + bid] =
            sRed[0][tid] + sRed[1][tid] + sRed[2][tid] + sRed[3][tid];
    }
}

__global__ __launch_bounds__(1024)
void softncuts_finalize(const float* __restrict__ partials,
                        float* __restrict__ out) {
    __shared__ float red[64];
    const int tid = threadIdx.x;          // 0..1023
    const int group = tid >> 4;           // 0..63 = bb*16 + slot
    const int j0 = tid & 15;
    const int slot = group & 15;
    const int bb = group >> 4;

    const float* p = partials + slot * NBLK + bb * 256;
    float s = 0.f;
#pragma unroll
    for (int k = 0; k < 16; ++k) s += p[j0 + 16 * k];
    for (int off = 8; off; off >>= 1) s += __shfl_down(s, off, 16);
    if (j0 == 0) red[group] = s;
    __syncthreads();

    if (tid < 4) {
        float accv = 0.f;
#pragma unroll
        for (int k = 0; k < 8; ++k)
            accv += red[tid * 16 + k] / red[tid * 16 + 8 + k];
        out[tid] = 8.0f - accv;
    }
}

extern "C" void kernel_launch(void* const* d_in, const int* in_sizes, int n_in,
                              void* d_out, int out_size, void* d_ws, size_t ws_size,
                              hipStream_t stream) {
    const float* batch = (const float*)d_in[0];
    const float* preds = (const float*)d_in[1];
    float* out      = (float*)d_out;
    float* partials = (float*)d_ws;   // 16*NBLK floats = 64 KB

    softncuts_main<<<dim3(NBLK), dim3(NT), 0, stream>>>(batch, preds, partials);
    softncuts_finalize<<<dim3(1), dim3(1024), 0, stream>>>(partials, out);
}